// Round 7
// baseline (117.580 us; speedup 1.0000x reference)
//
#include <hip/hip_runtime.h>
#include <hip/hip_bf16.h>

// SelfAttention: N=2, S=2048, E=1024, H=16, D=64.
// Round 7: 32 q-rows per wave (2 MFMA row-blocks) -> K/V fragment reads feed
// 2 MFMAs each (LDS frag traffic per unit work x0.6). Same for out_proj
// (128x64 tiles). gload_lds staging + swizzles + swapped QK^T + cvt_pk pack +
// ones-MFMA rowsum retained from round 6.

#define S_LEN  2048
#define EMB    1024
#define NHEAD  16
#define DHEAD  64
#define NBATCH 2

typedef float              f32x4    __attribute__((ext_vector_type(4)));
typedef __bf16             bf16x8   __attribute__((ext_vector_type(8)));
typedef unsigned short     ushort8v __attribute__((ext_vector_type(8)));
typedef unsigned long long u64;

union FragU { ushort8v u; bf16x8 b; };

__device__ __forceinline__ unsigned short f2b(float f) {
  union { __hip_bfloat16 h; unsigned short u; } c;
  c.h = __float2bfloat16(f);
  return c.u;
}

__device__ __forceinline__ unsigned int cvt_pk_bf16(float lo, float hi) {
  unsigned int r;
  asm("v_cvt_pk_bf16_f32 %0, %1, %2" : "=v"(r) : "v"(lo), "v"(hi));
  return r;
}

// async global->LDS, 16B per lane, dest = uniform base + lane*16
#define GLD16(g, l)                                                            \
  __builtin_amdgcn_global_load_lds(                                            \
      (__attribute__((address_space(1))) void*)(g),                            \
      (__attribute__((address_space(3))) void*)(l), 16, 0, 0)

// ------------------------------------------------------------- f32 -> bf16
__global__ __launch_bounds__(256) void cvt_bf16(const float* __restrict__ X,
                                                unsigned short* __restrict__ Y) {
  const size_t i = ((size_t)blockIdx.x * 256 + threadIdx.x) * 8;
  float4 a = *reinterpret_cast<const float4*>(X + i);
  float4 b = *reinterpret_cast<const float4*>(X + i + 4);
  ushort8v u;
  u[0] = f2b(a.x); u[1] = f2b(a.y); u[2] = f2b(a.z); u[3] = f2b(a.w);
  u[4] = f2b(b.x); u[5] = f2b(b.y); u[6] = f2b(b.z); u[7] = f2b(b.w);
  *reinterpret_cast<ushort8v*>(Y + i) = u;
}

// ------------------------------------------------- V -> bf16 [n][h][d][s]
__global__ __launch_bounds__(256) void transpose_v(const float* __restrict__ V,
                                                   unsigned short* __restrict__ Vt) {
  __shared__ unsigned short T[64][72];
  const int bid = blockIdx.x;
  const int sb = bid & 31, h = (bid >> 5) & 15, n = bid >> 9;
  const int t = threadIdx.x;
  const int r = t >> 2, cb = (t & 3) * 16;

  const float* src = V + ((size_t)(n * S_LEN + sb * 64 + r)) * EMB + h * DHEAD + cb;
  ushort8v u0, u1;
#pragma unroll
  for (int j = 0; j < 2; ++j) {
    float4 x = *reinterpret_cast<const float4*>(src + j * 4);
    u0[j*4+0] = f2b(x.x); u0[j*4+1] = f2b(x.y); u0[j*4+2] = f2b(x.z); u0[j*4+3] = f2b(x.w);
    float4 y = *reinterpret_cast<const float4*>(src + 8 + j * 4);
    u1[j*4+0] = f2b(y.x); u1[j*4+1] = f2b(y.y); u1[j*4+2] = f2b(y.z); u1[j*4+3] = f2b(y.w);
  }
  *reinterpret_cast<ushort8v*>(&T[r][cb])     = u0;
  *reinterpret_cast<ushort8v*>(&T[r][cb + 8]) = u1;
  __syncthreads();

  const int d = t >> 2, sc_ = (t & 3) * 16;
  ushort8v o0, o1;
#pragma unroll
  for (int j = 0; j < 8; ++j) { o0[j] = T[sc_ + j][d]; o1[j] = T[sc_ + 8 + j][d]; }
  unsigned short* dst = Vt + ((size_t)((n * NHEAD + h) * DHEAD + d)) * S_LEN + sb * 64 + sc_;
  *reinterpret_cast<ushort8v*>(dst)     = o0;
  *reinterpret_cast<ushort8v*>(dst + 8) = o1;
}

// ------------------------------------------------------------ mask bitmap
__global__ __launch_bounds__(256) void pack_mask(const int* __restrict__ M,
                                                 u64* __restrict__ Mb) {
  const size_t idx = (size_t)blockIdx.x * 256 + threadIdx.x;
  const int v = M[idx];
  u64 b = __ballot(v != 0);
  if ((threadIdx.x & 63) == 0) Mb[idx >> 6] = b;
}

// ---------------------------------------------------------------- attention
__global__ __launch_bounds__(256) void attn_fwd(
    const unsigned short* __restrict__ Kb,   // bf16 [n][s][E]
    const unsigned short* __restrict__ Vtg,  // bf16 [n][h][d][s]
    const float* __restrict__ Qg,            // f32  [n][s][E]
    const u64* __restrict__ Mbit,            // [n][s][S/64]
    unsigned short* __restrict__ Og)         // bf16 [n][s][E]
{
  __shared__ __attribute__((aligned(16))) unsigned short Kl[2][4096];
  __shared__ __attribute__((aligned(16))) unsigned short Vl[2][4096];
  __shared__ __attribute__((aligned(16))) unsigned short Pl[4][2048];

  const int bid = blockIdx.x;
  const int qb = bid & 15, h = (bid >> 4) & 15, n = bid >> 8;
  const int tid = threadIdx.x;
  const int w = tid >> 6, l = tid & 63, lg = l >> 4, li = l & 15;
  const int lg4 = lg * 4;
  const int q0w = qb * 128 + w * 32;   // this wave's 32 q-rows

  // Q fragments (B operand), two 16-row blocks g=0,1
  FragU qf[2][2];
#pragma unroll
  for (int g = 0; g < 2; ++g) {
    const float* qp = Qg + (size_t)(n * S_LEN + q0w + g * 16 + li) * EMB + h * DHEAD + lg * 8;
#pragma unroll
    for (int s = 0; s < 2; ++s) {
      float4 a = *reinterpret_cast<const float4*>(qp + s * 32);
      float4 b = *reinterpret_cast<const float4*>(qp + s * 32 + 4);
      ushort8v u;
      u[0] = f2b(a.x); u[1] = f2b(a.y); u[2] = f2b(a.z); u[3] = f2b(a.w);
      u[4] = f2b(b.x); u[5] = f2b(b.y); u[6] = f2b(b.z); u[7] = f2b(b.w);
      qf[g][s].u = u;
    }
  }

  FragU ones;
#pragma unroll
  for (int j = 0; j < 8; ++j) ones.u[j] = 0x3F80;   // bf16 1.0

  f32x4 acc[2][4];
#pragma unroll
  for (int g = 0; g < 2; ++g)
#pragma unroll
    for (int c = 0; c < 4; ++c) acc[g][c] = (f32x4){0.f, 0.f, 0.f, 0.f};
  f32x4 lacc[2];
  lacc[0] = (f32x4){0.f, 0.f, 0.f, 0.f};
  lacc[1] = (f32x4){0.f, 0.f, 0.f, 0.f};

  // gload_lds staging (rule-21 triple: linear LDS dest, inverse-swizzled
  // global source, swizzled reads)
  const int srow8  = tid >> 3;
  const int schunk = (tid & 7) * 16;
  const int ssw    = (srow8 & 7) << 4;
  const char* kbase = (const char*)Kb +
      ((size_t)n * S_LEN + srow8) * (EMB * 2) + h * DHEAD * 2 + (schunk ^ ssw);
  const char* vbase = (const char*)Vtg +
      ((size_t)((n * NHEAD + h) * DHEAD) + srow8) * (S_LEN * 2) + (schunk ^ ssw);

  const int rsw = (li & 7) << 4;

  // per-wave P buffer: 32 rows x 128B; swizzle (li&7)<<4 (row&7 == li&7)
  char* Pw = (char*)&Pl[w][0];
  const int psw = (li & 7) << 4;

  const u64* Mq0 = Mbit + ((size_t)n * S_LEN + q0w + li) * (S_LEN / 64);
  const u64* Mq1 = Mq0 + 16 * (S_LEN / 64);

#define ATTN_STAGE(BUF, TILE) do {                                             \
    const char* kb_ = kbase + (size_t)(TILE) * (64 * 2048);                    \
    const char* vb_ = vbase + (size_t)(TILE) * 128;                            \
    GLD16(kb_,             (char*)Kl + (BUF) * 8192 + w * 1024);               \
    GLD16(kb_ + 32 * 2048, (char*)Kl + (BUF) * 8192 + 4096 + w * 1024);        \
    GLD16(vb_,             (char*)Vl + (BUF) * 8192 + w * 1024);               \
    GLD16(vb_ + 32 * 4096, (char*)Vl + (BUF) * 8192 + 4096 + w * 1024);        \
  } while (0)

#define ATTN_TILE(BUF, IT) do {                                                \
    __syncthreads();                                                           \
    if ((IT) + 1 < 32) ATTN_STAGE((BUF) ^ 1, (IT) + 1);                        \
    const u64 mr0_ = Mq0[(IT)];                                                \
    const u64 mr1_ = Mq1[(IT)];                                                \
    unsigned int nib_[2][4];                                                   \
    nib_[0][0] = (unsigned int)mr0_ >> lg4;                                    \
    nib_[0][1] = (unsigned int)mr0_ >> (16 + lg4);                             \
    nib_[0][2] = (unsigned int)(mr0_ >> 32) >> lg4;                            \
    nib_[0][3] = (unsigned int)(mr0_ >> 32) >> (16 + lg4);                     \
    nib_[1][0] = (unsigned int)mr1_ >> lg4;                                    \
    nib_[1][1] = (unsigned int)mr1_ >> (16 + lg4);                             \
    nib_[1][2] = (unsigned int)(mr1_ >> 32) >> lg4;                            \
    nib_[1][3] = (unsigned int)(mr1_ >> 32) >> (16 + lg4);                     \
    f32x4 sc_[2][4];                                                           \
    __builtin_amdgcn_s_setprio(1);                                             \
    _Pragma("unroll") for (int c = 0; c < 4; ++c) {                            \
      FragU kf0_, kf1_;                                                        \
      kf0_.u = *reinterpret_cast<const ushort8v*>(                             \
          (char*)Kl + (BUF) * 8192 + ((c * 16 + li) * 128 + ((lg * 16) ^ rsw)));      \
      kf1_.u = *reinterpret_cast<const ushort8v*>(                             \
          (char*)Kl + (BUF) * 8192 + ((c * 16 + li) * 128 + ((64 + lg * 16) ^ rsw))); \
      _Pragma("unroll") for (int g = 0; g < 2; ++g) {                          \
        f32x4 a_ = (f32x4){0.f, 0.f, 0.f, 0.f};                                \
        a_ = __builtin_amdgcn_mfma_f32_16x16x32_bf16(kf0_.b, qf[g][0].b, a_, 0, 0, 0); \
        a_ = __builtin_amdgcn_mfma_f32_16x16x32_bf16(kf1_.b, qf[g][1].b, a_, 0, 0, 0); \
        sc_[g][c] = a_;                                                        \
      }                                                                        \
    }                                                                          \
    __builtin_amdgcn_s_setprio(0);                                             \
    _Pragma("unroll") for (int g = 0; g < 2; ++g) {                            \
      _Pragma("unroll") for (int c = 0; c < 4; ++c) {                          \
        float p_[4];                                                           \
        _Pragma("unroll") for (int r = 0; r < 4; ++r) {                        \
          float t_ = __builtin_amdgcn_exp2f(                                   \
              __builtin_fmaf(sc_[g][c][r], 0.04508422002778011f, -5.770780163555854f)); \
          p_[r] = (nib_[g][c] & (1u << r)) ? t_ : 0.f;                         \
        }                                                                      \
        uint2 pk_;                                                             \
        pk_.x = cvt_pk_bf16(p_[0], p_[1]);                                     \
        pk_.y = cvt_pk_bf16(p_[2], p_[3]);                                     \
        *reinterpret_cast<uint2*>(Pw + (g * 16 + li) * 128 +                   \
                                  ((c * 32 + lg * 8) ^ psw)) = pk_;            \
      }                                                                        \
    }                                                                          \
    FragU pf_[2][2];                                                           \
    _Pragma("unroll") for (int g = 0; g < 2; ++g) {                            \
      pf_[g][0].u = *reinterpret_cast<const ushort8v*>(                        \
          Pw + (g * 16 + li) * 128 + ((lg * 16) ^ psw));                       \
      pf_[g][1].u = *reinterpret_cast<const ushort8v*>(                        \
          Pw + (g * 16 + li) * 128 + ((64 + lg * 16) ^ psw));                  \
    }                                                                          \
    __builtin_amdgcn_s_setprio(1);                                             \
    _Pragma("unroll") for (int g = 0; g < 2; ++g) {                            \
      lacc[g] = __builtin_amdgcn_mfma_f32_16x16x32_bf16(pf_[g][0].b, ones.b, lacc[g], 0, 0, 0); \
      lacc[g] = __builtin_amdgcn_mfma_f32_16x16x32_bf16(pf_[g][1].b, ones.b, lacc[g], 0, 0, 0); \
    }                                                                          \
    _Pragma("unroll") for (int c = 0; c < 4; ++c) {                            \
      FragU vf0_, vf1_;                                                        \
      vf0_.u = *reinterpret_cast<const ushort8v*>(                             \
          (char*)Vl + (BUF) * 8192 + ((c * 16 + li) * 128 + ((lg * 16) ^ rsw)));      \
      vf1_.u = *reinterpret_cast<const ushort8v*>(                             \
          (char*)Vl + (BUF) * 8192 + ((c * 16 + li) * 128 + ((64 + lg * 16) ^ rsw))); \
      _Pragma("unroll") for (int g = 0; g < 2; ++g) {                          \
        acc[g][c] = __builtin_amdgcn_mfma_f32_16x16x32_bf16(pf_[g][0].b, vf0_.b, acc[g][c], 0, 0, 0); \
        acc[g][c] = __builtin_amdgcn_mfma_f32_16x16x32_bf16(pf_[g][1].b, vf1_.b, acc[g][c], 0, 0, 0); \
      }                                                                        \
    }                                                                          \
    __builtin_amdgcn_s_setprio(0);                                             \
  } while (0)

  ATTN_STAGE(0, 0);
  for (int it = 0; it < 32; it += 2) {
    ATTN_TILE(0, it);
    ATTN_TILE(1, it + 1);
  }

  // ---- epilogue: normalize, store bf16 ----
#pragma unroll
  for (int g = 0; g < 2; ++g) {
    float rin[4];
#pragma unroll
    for (int r = 0; r < 4; ++r) rin[r] = 1.0f / lacc[g][r];
#pragma unroll
    for (int c = 0; c < 4; ++c) {
#pragma unroll
      for (int r = 0; r < 4; ++r) {
        const int qg_ = q0w + g * 16 + lg * 4 + r;
        Og[(size_t)(n * S_LEN + qg_) * EMB + h * DHEAD + c * 16 + li] =
            f2b(acc[g][c][r] * rin[r]);
      }
    }
  }
}

// ---------------------------------------------------------------- projection
__global__ __launch_bounds__(256) void out_proj(
    const unsigned short* __restrict__ A,   // bf16 [4096][1024]
    const unsigned short* __restrict__ W,   // bf16 [1024][1024]
    const float* __restrict__ bias,
    float* __restrict__ Y)                  // f32 [4096][1024]
{
  __shared__ __attribute__((aligned(16))) unsigned short At[2][8192];
  __shared__ __attribute__((aligned(16))) unsigned short Bt[2][4096];

  const int bid = blockIdx.x;
  const int nb = bid & 15, mb = bid >> 4;        // mb 0..31
  const int tid = threadIdx.x;
  const int w = tid >> 6, l = tid & 63, lg = l >> 4, li = l & 15;
  const int m0 = mb * 128, n0 = nb * 64;

  f32x4 acc[2][4];
#pragma unroll
  for (int g = 0; g < 2; ++g)
#pragma unroll
    for (int c = 0; c < 4; ++c) acc[g][c] = (f32x4){0.f, 0.f, 0.f, 0.f};

  const int srow8  = tid >> 3;
  const int schunk = (tid & 7) * 16;
  const int ssw    = (srow8 & 7) << 4;
  const char* abase = (const char*)A + ((size_t)m0 + srow8) * (EMB * 2) + (schunk ^ ssw);
  const char* bbase = (const char*)W + ((size_t)n0 + srow8) * (EMB * 2) + (schunk ^ ssw);
  const int rsw = (li & 7) << 4;

#define PROJ_STAGE(BUF, KK) do {                                               \
    const char* ab_ = abase + (KK) * 128;                                      \
    const char* bb_ = bbase + (KK) * 128;                                      \
    GLD16(ab_,             (char*)At + (BUF) * 16384 + w * 1024);              \
    GLD16(ab_ + 32 * 2048, (char*)At + (BUF) * 16384 + 4096 + w * 1024);       \
    GLD16(ab_ + 64 * 2048, (char*)At + (BUF) * 16384 + 8192 + w * 1024);       \
    GLD16(ab_ + 96 * 2048, (char*)At + (BUF) * 16384 + 12288 + w * 1024);      \
    GLD16(bb_,             (char*)Bt + (BUF) * 8192 + w * 1024);               \
    GLD16(bb_ + 32 * 2048, (char*)Bt + (BUF) * 8192 + 4096 + w * 1024);        \
  } while (0)

#define PROJ_TILE(BUF, KK) do {                                                \
    __syncthreads();                                                           \
    if ((KK) + 1 < 16) PROJ_STAGE((BUF) ^ 1, (KK) + 1);                        \
    __builtin_amdgcn_s_setprio(1);                                             \
    _Pragma("unroll") for (int s = 0; s < 2; ++s) {                            \
      FragU af_[2];                                                            \
      _Pragma("unroll") for (int g = 0; g < 2; ++g)                            \
        af_[g].u = *reinterpret_cast<const ushort8v*>(                         \
            (char*)At + (BUF) * 16384 +                                        \
            ((w * 32 + g * 16 + li) * 128 + ((s * 64 + lg * 16) ^ rsw)));      \
      _Pragma("unroll") for (int c = 0; c < 4; ++c) {                          \
        FragU bf_;                                                             \
        bf_.u = *reinterpret_cast<const ushort8v*>(                            \
            (char*)Bt + (BUF) * 8192 +                                         \
            ((c * 16 + li) * 128 + ((s * 64 + lg * 16) ^ rsw)));               \
        acc[0][c] = __builtin_amdgcn_mfma_f32_16x16x32_bf16(af_[0].b, bf_.b, acc[0][c], 0, 0, 0); \
        acc[1][c] = __builtin_amdgcn_mfma_f32_16x16x32_bf16(af_[1].b, bf_.b, acc[1][c], 0, 0, 0); \
      }                                                                        \
    }                                                                          \
    __builtin_amdgcn_s_setprio(0);                                             \
  } while (0)

  PROJ_STAGE(0, 0);
  for (int kk = 0; kk < 16; kk += 2) {
    PROJ_TILE(0, kk);
    PROJ_TILE(1, kk + 1);
  }

#pragma unroll
  for (int g = 0; g < 2; ++g)
#pragma unroll
    for (int c = 0; c < 4; ++c) {
      const float bv = bias[n0 + c * 16 + li];
#pragma unroll
      for (int r = 0; r < 4; ++r) {
        const int row = m0 + w * 32 + g * 16 + lg * 4 + r;
        Y[(size_t)row * EMB + n0 + c * 16 + li] = acc[g][c][r] + bv;
      }
    }
}

// ---------------------------------------------------------------- launch
extern "C" void kernel_launch(void* const* d_in, const int* in_sizes, int n_in,
                              void* d_out, int out_size, void* d_ws, size_t ws_size,
                              hipStream_t stream) {
  const float* Vg = (const float*)d_in[0];
  const float* Kg = (const float*)d_in[1];
  const float* Qg = (const float*)d_in[2];
  const int*   Mg = (const int*)d_in[3];
  const float* Wo = (const float*)d_in[4];
  const float* bo = (const float*)d_in[5];
  float* Y = (float*)d_out;

  char* ws = (char*)d_ws;
  unsigned short* Og   = (unsigned short*)(ws);                       //  8 MB
  unsigned short* Wb   = (unsigned short*)(ws + (8u << 20));          //  2 MB
  unsigned short* Kb16 = (unsigned short*)(ws + (10u << 20));         //  8 MB
  unsigned short* Vt   = (unsigned short*)(ws + (18u << 20));         //  8 MB
  u64*            Mbit = (u64*)(ws + (26u << 20));                    //  1 MB

  const int elemsQK = NBATCH * S_LEN * EMB;  // 4,194,304

  hipLaunchKernelGGL(cvt_bf16, dim3(EMB * EMB / (256 * 8)), dim3(256), 0, stream, Wo, Wb);
  hipLaunchKernelGGL(cvt_bf16, dim3(elemsQK / (256 * 8)), dim3(256), 0, stream, Kg, Kb16);
  hipLaunchKernelGGL(transpose_v, dim3(NBATCH * NHEAD * (S_LEN / 64)), dim3(256), 0, stream, Vg, Vt);
  hipLaunchKernelGGL(pack_mask, dim3(NBATCH * S_LEN * S_LEN / 256), dim3(256), 0, stream, Mg, Mbit);
  hipLaunchKernelGGL(attn_fwd, dim3(NBATCH * NHEAD * (S_LEN / 128)), dim3(256), 0, stream,
                     Kb16, Vt, Qg, Mbit, Og);
  hipLaunchKernelGGL(out_proj, dim3((NBATCH * S_LEN / 128) * (EMB / 64)), dim3(256), 0, stream,
                     Og, Wb, bo, Y);
}

// Round 8
// 102.997 us; speedup vs baseline: 1.1416x; 1.1416x over previous
//
#include <hip/hip_runtime.h>
#include <hip/hip_bf16.h>

// SelfAttention: N=2, S=2048, E=1024, H=16, D=64.
// Round 8: 8-wave blocks, 32q/wave, KV split across wave groups (waves 0-3:
// kv[0,1024), waves 4-7: kv[1024,2048)), KVBLK=32. Fixed-max softmax makes
// partials additive -> LDS combine in epilogue (no global partials). gload_lds
// staging w/ rule-21 swizzle triples (K rows 128B: 3-bit XOR; V/P rows 64B:
// 2-bit XOR). Fused prep kernel. out_proj unchanged from round 7.

#define S_LEN  2048
#define EMB    1024
#define NHEAD  16
#define DHEAD  64
#define NBATCH 2

typedef float              f32x4    __attribute__((ext_vector_type(4)));
typedef __bf16             bf16x8   __attribute__((ext_vector_type(8)));
typedef unsigned short     ushort8v __attribute__((ext_vector_type(8)));
typedef unsigned long long u64;

union FragU { ushort8v u; bf16x8 b; };

__device__ __forceinline__ unsigned short f2b(float f) {
  union { __hip_bfloat16 h; unsigned short u; } c;
  c.h = __float2bfloat16(f);
  return c.u;
}

__device__ __forceinline__ unsigned int cvt_pk_bf16(float lo, float hi) {
  unsigned int r;
  asm("v_cvt_pk_bf16_f32 %0, %1, %2" : "=v"(r) : "v"(lo), "v"(hi));
  return r;
}

#define GLD16(g, l)                                                            \
  __builtin_amdgcn_global_load_lds(                                            \
      (__attribute__((address_space(1))) void*)(g),                            \
      (__attribute__((address_space(3))) void*)(l), 16, 0, 0)

// ------------------------------------------------------- fused prep kernel
// blocks [0,512): W f32->bf16 | [512,2560): K f32->bf16 | [2560,3584):
// V transpose -> bf16 [n][h][d][s] | [3584,11776): mask -> u64 bitmap
__global__ __launch_bounds__(256) void prep(
    const float* __restrict__ Wo, unsigned short* __restrict__ Wb,
    const float* __restrict__ Kg, unsigned short* __restrict__ Kb,
    const float* __restrict__ Vg, unsigned short* __restrict__ Vt,
    const int* __restrict__ Mg,   u64* __restrict__ Mb)
{
  const int bid = blockIdx.x;
  const int tid = threadIdx.x;
  if (bid < 2560) {                      // cvt W (512 blocks) or K (2048)
    const float* X = (bid < 512) ? Wo : Kg;
    unsigned short* Y = (bid < 512) ? Wb : Kb;
    const int bb = (bid < 512) ? bid : bid - 512;
    const size_t i = ((size_t)bb * 256 + tid) * 8;
    float4 a = *reinterpret_cast<const float4*>(X + i);
    float4 b = *reinterpret_cast<const float4*>(X + i + 4);
    ushort8v u;
    u[0] = f2b(a.x); u[1] = f2b(a.y); u[2] = f2b(a.z); u[3] = f2b(a.w);
    u[4] = f2b(b.x); u[5] = f2b(b.y); u[6] = f2b(b.z); u[7] = f2b(b.w);
    *reinterpret_cast<ushort8v*>(Y + i) = u;
  } else if (bid < 3584) {               // transpose V (1024 blocks)
    __shared__ unsigned short T[64][72];
    const int b2 = bid - 2560;
    const int sb = b2 & 31, h = (b2 >> 5) & 15, n = b2 >> 9;
    const int r = tid >> 2, cb = (tid & 3) * 16;
    const float* src = Vg + ((size_t)(n * S_LEN + sb * 64 + r)) * EMB + h * DHEAD + cb;
    ushort8v u0, u1;
#pragma unroll
    for (int j = 0; j < 2; ++j) {
      float4 x = *reinterpret_cast<const float4*>(src + j * 4);
      u0[j*4+0] = f2b(x.x); u0[j*4+1] = f2b(x.y); u0[j*4+2] = f2b(x.z); u0[j*4+3] = f2b(x.w);
      float4 y = *reinterpret_cast<const float4*>(src + 8 + j * 4);
      u1[j*4+0] = f2b(y.x); u1[j*4+1] = f2b(y.y); u1[j*4+2] = f2b(y.z); u1[j*4+3] = f2b(y.w);
    }
    *reinterpret_cast<ushort8v*>(&T[r][cb])     = u0;
    *reinterpret_cast<ushort8v*>(&T[r][cb + 8]) = u1;
    __syncthreads();
    const int d = tid >> 2, sc_ = (tid & 3) * 16;
    ushort8v o0, o1;
#pragma unroll
    for (int j = 0; j < 8; ++j) { o0[j] = T[sc_ + j][d]; o1[j] = T[sc_ + 8 + j][d]; }
    unsigned short* dst = Vt + ((size_t)((n * NHEAD + h) * DHEAD + d)) * S_LEN + sb * 64 + sc_;
    *reinterpret_cast<ushort8v*>(dst)     = o0;
    *reinterpret_cast<ushort8v*>(dst + 8) = o1;
  } else {                               // pack mask (8192 blocks, 1024 ints each)
    const int b3 = bid - 3584;
    const size_t base = (size_t)b3 * 1024 + (tid >> 6) * 256;
    const int l = tid & 63;
#pragma unroll
    for (int j = 0; j < 4; ++j) {
      const int v = Mg[base + j * 64 + l];
      u64 bj = __ballot(v != 0);
      if (l == 0) Mb[base / 64 + j] = bj;
    }
  }
}

// ---------------------------------------------------------------- attention
// LDS map (48KB): K [dbuf2][sp2][4KB] @0, V [dbuf2][sp2][4KB] @16K, P [w8][2KB] @32K
#define KBASE 0
#define VBASE 16384
#define PBASE 32768

__global__ __launch_bounds__(512, 4) void attn_fwd(
    const unsigned short* __restrict__ Kb,   // bf16 [n][s][E]
    const unsigned short* __restrict__ Vtg,  // bf16 [n][h][d][s]
    const float* __restrict__ Qg,            // f32  [n][s][E]
    const u64* __restrict__ Mbit,            // [n][s][32]
    unsigned short* __restrict__ Og)         // bf16 [n][s][E]
{
  __shared__ __attribute__((aligned(16))) char SMEM[49152];

  const int bid = blockIdx.x;
  const int qb = bid & 15, h = (bid >> 4) & 15, n = bid >> 8;
  const int nh = n * NHEAD + h;
  const int tid = threadIdx.x;
  const int w = tid >> 6, sp = w >> 2, wq = w & 3;
  const int l = tid & 63, lg = l >> 4, li = l & 15;
  const int lg4 = lg * 4;
  const int q0w = qb * 128 + wq * 32;

  // Q fragments (B operand), 2 q-blocks g
  FragU qf[2][2];
#pragma unroll
  for (int g = 0; g < 2; ++g) {
    const float* qp = Qg + (size_t)(n * S_LEN + q0w + g * 16 + li) * EMB + h * DHEAD + lg * 8;
#pragma unroll
    for (int s = 0; s < 2; ++s) {
      float4 a = *reinterpret_cast<const float4*>(qp + s * 32);
      float4 b = *reinterpret_cast<const float4*>(qp + s * 32 + 4);
      ushort8v u;
      u[0] = f2b(a.x); u[1] = f2b(a.y); u[2] = f2b(a.z); u[3] = f2b(a.w);
      u[4] = f2b(b.x); u[5] = f2b(b.y); u[6] = f2b(b.z); u[7] = f2b(b.w);
      qf[g][s].u = u;
    }
  }

  FragU ones;
#pragma unroll
  for (int j = 0; j < 8; ++j) ones.u[j] = 0x3F80;

  f32x4 acc[2][4];
#pragma unroll
  for (int g = 0; g < 2; ++g)
#pragma unroll
    for (int c = 0; c < 4; ++c) acc[g][c] = (f32x4){0.f, 0.f, 0.f, 0.f};
  f32x4 lacc[2];
  lacc[0] = (f32x4){0.f, 0.f, 0.f, 0.f};
  lacc[1] = (f32x4){0.f, 0.f, 0.f, 0.f};

  // staging (each 4-wave group stages its own split's K/V tile)
  const int t = tid & 255;
  const int krow = t >> 3;                  // 0..31
  const char* kbase = (const char*)Kb +
      ((size_t)n * S_LEN + sp * 1024 + krow) * (EMB * 2) + h * 128 +
      (((t & 7) * 16) ^ ((krow & 7) << 4));
  const int vrow = t >> 2;                  // 0..63 (d)
  const char* vbase = (const char*)Vtg +
      ((size_t)nh * DHEAD + vrow) * (S_LEN * 2) + sp * 2048 +
      (((t & 3) * 16) ^ ((vrow & 3) << 4));

  const int rsw  = (li & 7) << 4;   // K frag-read swizzle (128B rows)
  const int vrsw = (li & 3) << 4;   // V frag-read swizzle (64B rows)
  const int psw  = (li & 3) << 4;   // P swizzle (64B rows)

  char* Kme = SMEM + KBASE + sp * 4096;
  char* Vme = SMEM + VBASE + sp * 4096;
  char* Pw  = SMEM + PBASE + w * 2048;

  const u64* Mq0 = Mbit + ((size_t)n * S_LEN + q0w + li) * 32 + sp * 16;
  const u64* Mq1 = Mq0 + 16 * 32;

#define ATTN_STAGE(BUF, IT) do {                                               \
    GLD16(kbase + (size_t)(IT) * (32 * 2048), Kme + (BUF) * 8192 + t * 16);    \
    GLD16(vbase + (size_t)(IT) * 64,          Vme + (BUF) * 8192 + t * 16);    \
  } while (0)

#define ATTN_TILE(BUF, IT) do {                                                \
    __syncthreads();                                                           \
    if ((IT) + 1 < 32) ATTN_STAGE((BUF) ^ 1, (IT) + 1);                        \
    const u64 m0_ = Mq0[(IT) >> 1];                                            \
    const u64 m1_ = Mq1[(IT) >> 1];                                            \
    const unsigned int h0_ = ((IT) & 1) ? (unsigned int)(m0_ >> 32) : (unsigned int)m0_; \
    const unsigned int h1_ = ((IT) & 1) ? (unsigned int)(m1_ >> 32) : (unsigned int)m1_; \
    unsigned int nib_[2][2];                                                   \
    nib_[0][0] = h0_ >> lg4;  nib_[0][1] = h0_ >> (16 + lg4);                  \
    nib_[1][0] = h1_ >> lg4;  nib_[1][1] = h1_ >> (16 + lg4);                  \
    f32x4 sc_[2][2];                                                           \
    __builtin_amdgcn_s_setprio(1);                                             \
    _Pragma("unroll") for (int cc = 0; cc < 2; ++cc) {                         \
      FragU kf0_, kf1_;                                                        \
      kf0_.u = *reinterpret_cast<const ushort8v*>(                             \
          Kme + (BUF) * 8192 + ((cc * 16 + li) * 128 + ((lg * 16) ^ rsw)));    \
      kf1_.u = *reinterpret_cast<const ushort8v*>(                             \
          Kme + (BUF) * 8192 + ((cc * 16 + li) * 128 + ((64 + lg * 16) ^ rsw))); \
      _Pragma("unroll") for (int g = 0; g < 2; ++g) {                          \
        f32x4 a_ = (f32x4){0.f, 0.f, 0.f, 0.f};                                \
        a_ = __builtin_amdgcn_mfma_f32_16x16x32_bf16(kf0_.b, qf[g][0].b, a_, 0, 0, 0); \
        a_ = __builtin_amdgcn_mfma_f32_16x16x32_bf16(kf1_.b, qf[g][1].b, a_, 0, 0, 0); \
        sc_[g][cc] = a_;                                                       \
      }                                                                        \
    }                                                                          \
    __builtin_amdgcn_s_setprio(0);                                             \
    _Pragma("unroll") for (int g = 0; g < 2; ++g) {                            \
      _Pragma("unroll") for (int cc = 0; cc < 2; ++cc) {                       \
        float p_[4];                                                           \
        _Pragma("unroll") for (int r = 0; r < 4; ++r) {                        \
          float t_ = __builtin_amdgcn_exp2f(                                   \
              __builtin_fmaf(sc_[g][cc][r], 0.04508422002778011f, -5.770780163555854f)); \
          p_[r] = (nib_[g][cc] & (1u << r)) ? t_ : 0.f;                        \
        }                                                                      \
        uint2 pk_;                                                             \
        pk_.x = cvt_pk_bf16(p_[0], p_[1]);                                     \
        pk_.y = cvt_pk_bf16(p_[2], p_[3]);                                     \
        *reinterpret_cast<uint2*>(Pw + (g * 16 + li) * 64 +                    \
                                  ((cc * 32 + lg * 8) ^ psw)) = pk_;           \
      }                                                                        \
    }                                                                          \
    FragU pf_[2];                                                              \
    pf_[0].u = *reinterpret_cast<const ushort8v*>(Pw + li * 64 + ((lg * 16) ^ psw));        \
    pf_[1].u = *reinterpret_cast<const ushort8v*>(Pw + (16 + li) * 64 + ((lg * 16) ^ psw)); \
    __builtin_amdgcn_s_setprio(1);                                             \
    lacc[0] = __builtin_amdgcn_mfma_f32_16x16x32_bf16(pf_[0].b, ones.b, lacc[0], 0, 0, 0); \
    lacc[1] = __builtin_amdgcn_mfma_f32_16x16x32_bf16(pf_[1].b, ones.b, lacc[1], 0, 0, 0); \
    _Pragma("unroll") for (int c = 0; c < 4; ++c) {                            \
      FragU vf_;                                                               \
      vf_.u = *reinterpret_cast<const ushort8v*>(                              \
          Vme + (BUF) * 8192 + ((c * 16 + li) * 64 + ((lg * 16) ^ vrsw)));     \
      acc[0][c] = __builtin_amdgcn_mfma_f32_16x16x32_bf16(pf_[0].b, vf_.b, acc[0][c], 0, 0, 0); \
      acc[1][c] = __builtin_amdgcn_mfma_f32_16x16x32_bf16(pf_[1].b, vf_.b, acc[1][c], 0, 0, 0); \
    }                                                                          \
    __builtin_amdgcn_s_setprio(0);                                             \
  } while (0)

  ATTN_STAGE(0, 0);
  for (int it = 0; it < 32; it += 2) {
    ATTN_TILE(0, it);
    ATTN_TILE(1, it + 1);
  }

  // ---- combine the two KV splits via LDS, then normalize + store ----
  __syncthreads();
  if (sp == 1) {
#pragma unroll
    for (int g = 0; g < 2; ++g)
#pragma unroll
      for (int c = 0; c < 4; ++c)
        *reinterpret_cast<f32x4*>(SMEM + wq * 8192 + l * 128 +
                                  ((g * 64 + c * 16) ^ ((l & 7) << 4))) = acc[g][c];
    *reinterpret_cast<f32x4*>(SMEM + PBASE + w * 2048 + l * 32)      = lacc[0];
    *reinterpret_cast<f32x4*>(SMEM + PBASE + w * 2048 + l * 32 + 16) = lacc[1];
  }
  __syncthreads();
  if (sp == 0) {
    f32x4 pl[2];
    pl[0] = *reinterpret_cast<const f32x4*>(SMEM + PBASE + (w + 4) * 2048 + l * 32);
    pl[1] = *reinterpret_cast<const f32x4*>(SMEM + PBASE + (w + 4) * 2048 + l * 32 + 16);
#pragma unroll
    for (int g = 0; g < 2; ++g) {
      float rin[4];
#pragma unroll
      for (int r = 0; r < 4; ++r) rin[r] = 1.0f / (lacc[g][r] + pl[g][r]);
#pragma unroll
      for (int c = 0; c < 4; ++c) {
        f32x4 pa = *reinterpret_cast<const f32x4*>(
            SMEM + wq * 8192 + l * 128 + ((g * 64 + c * 16) ^ ((l & 7) << 4)));
#pragma unroll
        for (int r = 0; r < 4; ++r) {
          const int qg_ = q0w + g * 16 + lg * 4 + r;
          Og[(size_t)(n * S_LEN + qg_) * EMB + h * DHEAD + c * 16 + li] =
              f2b((acc[g][c][r] + pa[r]) * rin[r]);
        }
      }
    }
  }
}

// ---------------------------------------------------------------- projection
__global__ __launch_bounds__(256) void out_proj(
    const unsigned short* __restrict__ A,   // bf16 [4096][1024]
    const unsigned short* __restrict__ W,   // bf16 [1024][1024]
    const float* __restrict__ bias,
    float* __restrict__ Y)                  // f32 [4096][1024]
{
  __shared__ __attribute__((aligned(16))) unsigned short At[2][8192];
  __shared__ __attribute__((aligned(16))) unsigned short Bt[2][4096];

  const int bid = blockIdx.x;
  const int nb = bid & 15, mb = bid >> 4;
  const int tid = threadIdx.x;
  const int w = tid >> 6, l = tid & 63, lg = l >> 4, li = l & 15;
  const int m0 = mb * 128, n0 = nb * 64;

  f32x4 acc[2][4];
#pragma unroll
  for (int g = 0; g < 2; ++g)
#pragma unroll
    for (int c = 0; c < 4; ++c) acc[g][c] = (f32x4){0.f, 0.f, 0.f, 0.f};

  const int srow8  = tid >> 3;
  const int schunk = (tid & 7) * 16;
  const int ssw    = (srow8 & 7) << 4;
  const char* abase = (const char*)A + ((size_t)m0 + srow8) * (EMB * 2) + (schunk ^ ssw);
  const char* bbase = (const char*)W + ((size_t)n0 + srow8) * (EMB * 2) + (schunk ^ ssw);
  const int rsw = (li & 7) << 4;

#define PROJ_STAGE(BUF, KK) do {                                               \
    const char* ab_ = abase + (KK) * 128;                                      \
    const char* bb_ = bbase + (KK) * 128;                                      \
    GLD16(ab_,             (char*)At + (BUF) * 16384 + w * 1024);              \
    GLD16(ab_ + 32 * 2048, (char*)At + (BUF) * 16384 + 4096 + w * 1024);       \
    GLD16(ab_ + 64 * 2048, (char*)At + (BUF) * 16384 + 8192 + w * 1024);       \
    GLD16(ab_ + 96 * 2048, (char*)At + (BUF) * 16384 + 12288 + w * 1024);      \
    GLD16(bb_,             (char*)Bt + (BUF) * 8192 + w * 1024);               \
    GLD16(bb_ + 32 * 2048, (char*)Bt + (BUF) * 8192 + 4096 + w * 1024);        \
  } while (0)

#define PROJ_TILE(BUF, KK) do {                                                \
    __syncthreads();                                                           \
    if ((KK) + 1 < 16) PROJ_STAGE((BUF) ^ 1, (KK) + 1);                        \
    __builtin_amdgcn_s_setprio(1);                                             \
    _Pragma("unroll") for (int s = 0; s < 2; ++s) {                            \
      FragU af_[2];                                                            \
      _Pragma("unroll") for (int g = 0; g < 2; ++g)                            \
        af_[g].u = *reinterpret_cast<const ushort8v*>(                         \
            (char*)At + (BUF) * 16384 +                                        \
            ((w * 32 + g * 16 + li) * 128 + ((s * 64 + lg * 16) ^ rsw)));      \
      _Pragma("unroll") for (int c = 0; c < 4; ++c) {                          \
        FragU bf_;                                                             \
        bf_.u = *reinterpret_cast<const ushort8v*>(                            \
            (char*)Bt + (BUF) * 8192 +                                         \
            ((c * 16 + li) * 128 + ((s * 64 + lg * 16) ^ rsw)));               \
        acc[0][c] = __builtin_amdgcn_mfma_f32_16x16x32_bf16(af_[0].b, bf_.b, acc[0][c], 0, 0, 0); \
        acc[1][c] = __builtin_amdgcn_mfma_f32_16x16x32_bf16(af_[1].b, bf_.b, acc[1][c], 0, 0, 0); \
      }                                                                        \
    }                                                                          \
    __builtin_amdgcn_s_setprio(0);                                             \
  } while (0)

  PROJ_STAGE(0, 0);
  for (int kk = 0; kk < 16; kk += 2) {
    PROJ_TILE(0, kk);
    PROJ_TILE(1, kk + 1);
  }

#pragma unroll
  for (int g = 0; g < 2; ++g)
#pragma unroll
    for (int c = 0; c < 4; ++c) {
      const float bv = bias[n0 + c * 16 + li];
#pragma unroll
      for (int r = 0; r < 4; ++r) {
        const int row = m0 + w * 32 + g * 16 + lg * 4 + r;
        Y[(size_t)row * EMB + n0 + c * 16 + li] = acc[g][c][r] + bv;
      }
    }
}

// ---------------------------------------------------------------- launch
extern "C" void kernel_launch(void* const* d_in, const int* in_sizes, int n_in,
                              void* d_out, int out_size, void* d_ws, size_t ws_size,
                              hipStream_t stream) {
  const float* Vg = (const float*)d_in[0];
  const float* Kg = (const float*)d_in[1];
  const float* Qg = (const float*)d_in[2];
  const int*   Mg = (const int*)d_in[3];
  const float* Wo = (const float*)d_in[4];
  const float* bo = (const float*)d_in[5];
  float* Y = (float*)d_out;

  char* ws = (char*)d_ws;
  unsigned short* Og   = (unsigned short*)(ws);                       //  8 MB
  unsigned short* Wb   = (unsigned short*)(ws + (8u << 20));          //  2 MB
  unsigned short* Kb16 = (unsigned short*)(ws + (10u << 20));         //  8 MB
  unsigned short* Vt   = (unsigned short*)(ws + (18u << 20));         //  8 MB
  u64*            Mbit = (u64*)(ws + (26u << 20));                    //  1 MB

  hipLaunchKernelGGL(prep, dim3(11776), dim3(256), 0, stream,
                     Wo, Wb, Kg, Kb16, Vg, Vt, Mg, Mbit);
  hipLaunchKernelGGL(attn_fwd, dim3(NBATCH * NHEAD * (S_LEN / 128)), dim3(512), 0, stream,
                     Kb16, Vt, Qg, Mbit, Og);
  hipLaunchKernelGGL(out_proj, dim3((NBATCH * S_LEN / 128) * (EMB / 64)), dim3(256), 0, stream,
                     Og, Wb, bo, Y);
}

// Round 9
// 96.034 us; speedup vs baseline: 1.2244x; 1.0725x over previous
//
#include <hip/hip_runtime.h>
#include <hip/hip_bf16.h>

// SelfAttention: N=2, S=2048, E=1024, H=16, D=64.
// Round 9: attention on 32x32x16 MFMA (2x arithmetic intensity per LDS byte),
// in-register P via cvt_pk + v_permlane32_swap (NO P LDS round-trip),
// lane-local rowsum/normalization. KV-split 8-wave blocks, KVBLK=64,
// 128B LDS rows + 3-bit XOR swizzle everywhere. prep/out_proj = round 8.

#define S_LEN  2048
#define EMB    1024
#define NHEAD  16
#define DHEAD  64
#define NBATCH 2

typedef float              f32x4    __attribute__((ext_vector_type(4)));
typedef float              f32x16   __attribute__((ext_vector_type(16)));
typedef __bf16             bf16x8   __attribute__((ext_vector_type(8)));
typedef unsigned short     ushort8v __attribute__((ext_vector_type(8)));
typedef unsigned long long u64;

union FragU { ushort8v u; bf16x8 b; };
union BFrag { unsigned u32[4]; bf16x8 b; };

__device__ __forceinline__ unsigned short f2b(float f) {
  union { __hip_bfloat16 h; unsigned short u; } c;
  c.h = __float2bfloat16(f);
  return c.u;
}

__device__ __forceinline__ unsigned int cvt_pk_bf16(float lo, float hi) {
  unsigned int r;
  asm("v_cvt_pk_bf16_f32 %0, %1, %2" : "=v"(r) : "v"(lo), "v"(hi));
  return r;
}

// swap a.hi32lanes <-> b.lo32lanes (in place)
#define PSWAP(a, b) asm("v_permlane32_swap_b32 %0, %1" : "+v"(a), "+v"(b))

#define GLD16(g, l)                                                            \
  __builtin_amdgcn_global_load_lds(                                            \
      (__attribute__((address_space(1))) void*)(g),                            \
      (__attribute__((address_space(3))) void*)(l), 16, 0, 0)

// ------------------------------------------------------- fused prep kernel
__global__ __launch_bounds__(256) void prep(
    const float* __restrict__ Wo, unsigned short* __restrict__ Wb,
    const float* __restrict__ Kg, unsigned short* __restrict__ Kb,
    const float* __restrict__ Vg, unsigned short* __restrict__ Vt,
    const int* __restrict__ Mg,   u64* __restrict__ Mb)
{
  const int bid = blockIdx.x;
  const int tid = threadIdx.x;
  if (bid < 2560) {
    const float* X = (bid < 512) ? Wo : Kg;
    unsigned short* Y = (bid < 512) ? Wb : Kb;
    const int bb = (bid < 512) ? bid : bid - 512;
    const size_t i = ((size_t)bb * 256 + tid) * 8;
    float4 a = *reinterpret_cast<const float4*>(X + i);
    float4 b = *reinterpret_cast<const float4*>(X + i + 4);
    ushort8v u;
    u[0] = f2b(a.x); u[1] = f2b(a.y); u[2] = f2b(a.z); u[3] = f2b(a.w);
    u[4] = f2b(b.x); u[5] = f2b(b.y); u[6] = f2b(b.z); u[7] = f2b(b.w);
    *reinterpret_cast<ushort8v*>(Y + i) = u;
  } else if (bid < 3584) {
    __shared__ unsigned short T[64][72];
    const int b2 = bid - 2560;
    const int sb = b2 & 31, h = (b2 >> 5) & 15, n = b2 >> 9;
    const int r = tid >> 2, cb = (tid & 3) * 16;
    const float* src = Vg + ((size_t)(n * S_LEN + sb * 64 + r)) * EMB + h * DHEAD + cb;
    ushort8v u0, u1;
#pragma unroll
    for (int j = 0; j < 2; ++j) {
      float4 x = *reinterpret_cast<const float4*>(src + j * 4);
      u0[j*4+0] = f2b(x.x); u0[j*4+1] = f2b(x.y); u0[j*4+2] = f2b(x.z); u0[j*4+3] = f2b(x.w);
      float4 y = *reinterpret_cast<const float4*>(src + 8 + j * 4);
      u1[j*4+0] = f2b(y.x); u1[j*4+1] = f2b(y.y); u1[j*4+2] = f2b(y.z); u1[j*4+3] = f2b(y.w);
    }
    *reinterpret_cast<ushort8v*>(&T[r][cb])     = u0;
    *reinterpret_cast<ushort8v*>(&T[r][cb + 8]) = u1;
    __syncthreads();
    const int d = tid >> 2, sc_ = (tid & 3) * 16;
    ushort8v o0, o1;
#pragma unroll
    for (int j = 0; j < 8; ++j) { o0[j] = T[sc_ + j][d]; o1[j] = T[sc_ + 8 + j][d]; }
    unsigned short* dst = Vt + ((size_t)((n * NHEAD + h) * DHEAD + d)) * S_LEN + sb * 64 + sc_;
    *reinterpret_cast<ushort8v*>(dst)     = o0;
    *reinterpret_cast<ushort8v*>(dst + 8) = o1;
  } else {
    const int b3 = bid - 3584;
    const size_t base = (size_t)b3 * 1024 + (tid >> 6) * 256;
    const int l = tid & 63;
#pragma unroll
    for (int j = 0; j < 4; ++j) {
      const int v = Mg[base + j * 64 + l];
      u64 bj = __ballot(v != 0);
      if (l == 0) Mb[base / 64 + j] = bj;
    }
  }
}

// ---------------------------------------------------------------- attention
// LDS (64KB): K [sp][dbuf][8KB] @0, V [sp][dbuf][8KB] @32K. Epilogue reuses it.
__global__ __launch_bounds__(512, 4) void attn_fwd(
    const unsigned short* __restrict__ Kb,   // bf16 [n][s][E]
    const unsigned short* __restrict__ Vtg,  // bf16 [n][h][d][s]
    const float* __restrict__ Qg,            // f32  [n][s][E]
    const u64* __restrict__ Mbit,            // [n][s][32]
    unsigned short* __restrict__ Og)         // bf16 [n][s][E]
{
  __shared__ __attribute__((aligned(16))) char SMEM[65536];

  const int bid = blockIdx.x;
  const int qb = bid & 15, h = (bid >> 4) & 15, n = bid >> 8;
  const int nh = n * NHEAD + h;
  const int tid = threadIdx.x;
  const int w = tid >> 6, sp = w >> 2, wq = w & 3;
  const int l = tid & 63, q5 = l & 31, hi = l >> 5;
  const int hi4 = hi * 4;
  const int q0w = qb * 128 + wq * 32;
  const int qg = q0w + q5;                 // this lane's global q row

  // Q fragments (B operand of 32x32x16): lane holds Q[qg][k=s*16+hi*8+j]
  FragU qf[4];
  {
    const float* qp = Qg + ((size_t)(n * S_LEN + qg)) * EMB + h * DHEAD + hi * 8;
#pragma unroll
    for (int s = 0; s < 4; ++s) {
      float4 a = *reinterpret_cast<const float4*>(qp + s * 16);
      float4 b = *reinterpret_cast<const float4*>(qp + s * 16 + 4);
      ushort8v u;
      u[0] = f2b(a.x); u[1] = f2b(a.y); u[2] = f2b(a.z); u[3] = f2b(a.w);
      u[4] = f2b(b.x); u[5] = f2b(b.y); u[6] = f2b(b.z); u[7] = f2b(b.w);
      qf[s].u = u;
    }
  }

  f32x16 acc0 = {}, acc1 = {};
  float rsum = 0.f;

  // staging: 256 threads per split, thread t8: rows t8>>3 and +32, chunk t8&7
  const int t8 = tid & 255;
  const int srow = t8 >> 3, sc = t8 & 7;
  const char* kbase = (const char*)Kb +
      ((size_t)(n * S_LEN + sp * 1024 + srow)) * 2048 + h * 128 +
      ((sc * 16) ^ ((srow & 7) << 4));
  const char* vbase = (const char*)Vtg +
      ((size_t)(nh * DHEAD + srow)) * 4096 + sp * 2048 +
      ((sc * 16) ^ ((srow & 7) << 4));

  char* Ksp = SMEM + sp * 16384;
  char* Vsp = SMEM + 32768 + sp * 16384;
  const int fsw = (l & 7) << 4;            // frag-read swizzle (row&7 == l&7)

  const u64* Mq = Mbit + ((size_t)(n * S_LEN + qg)) * 32 + sp * 16;

#define ATTN_STAGE(BUF, IT) do {                                               \
    GLD16(kbase + (size_t)(IT) * 131072,          Ksp + (BUF) * 8192 + t8 * 16); \
    GLD16(kbase + (size_t)(IT) * 131072 + 65536,  Ksp + (BUF) * 8192 + 4096 + t8 * 16); \
    GLD16(vbase + (size_t)(IT) * 128,             Vsp + (BUF) * 8192 + t8 * 16); \
    GLD16(vbase + (size_t)(IT) * 128 + 131072,    Vsp + (BUF) * 8192 + 4096 + t8 * 16); \
  } while (0)

#define ATTN_TILE(BUF, IT) do {                                                \
    __syncthreads();                                                           \
    if ((IT) + 1 < 16) ATTN_STAGE((BUF) ^ 1, (IT) + 1);                        \
    const u64 mrow_ = Mq[(IT)];                                                \
    _Pragma("unroll") for (int b = 0; b < 2; ++b) {                            \
      f32x16 Sb = {};                                                          \
      __builtin_amdgcn_s_setprio(1);                                           \
      _Pragma("unroll") for (int s = 0; s < 4; ++s) {                          \
        FragU kf_;                                                             \
        kf_.u = *reinterpret_cast<const ushort8v*>(                            \
            Ksp + (BUF) * 8192 + ((b * 32 + q5) * 128 + ((s * 32 + hi * 16) ^ fsw))); \
        Sb = __builtin_amdgcn_mfma_f32_32x32x16_bf16(kf_.b, qf[s].b, Sb, 0, 0, 0); \
      }                                                                        \
      __builtin_amdgcn_s_setprio(0);                                           \
      const unsigned m32_ = b ? (unsigned)(mrow_ >> 32) : (unsigned)mrow_;     \
      float p_[16];                                                            \
      _Pragma("unroll") for (int t = 0; t < 4; ++t) {                          \
        const unsigned nib_ = m32_ >> (8 * t + hi4);                           \
        _Pragma("unroll") for (int e = 0; e < 4; ++e) {                        \
          const int r = 4 * t + e;                                             \
          float ex_ = __builtin_amdgcn_exp2f(                                  \
              __builtin_fmaf(Sb[r], 0.04508422002778011f, -5.770780163555854f)); \
          p_[r] = ((nib_ >> e) & 1u) ? ex_ : 0.f;                              \
          rsum += p_[r];                                                       \
        }                                                                      \
      }                                                                        \
      unsigned U0 = cvt_pk_bf16(p_[0],  p_[1]),  U1 = cvt_pk_bf16(p_[2],  p_[3]); \
      unsigned U2 = cvt_pk_bf16(p_[4],  p_[5]),  U3 = cvt_pk_bf16(p_[6],  p_[7]); \
      unsigned U4 = cvt_pk_bf16(p_[8],  p_[9]),  U5 = cvt_pk_bf16(p_[10], p_[11]); \
      unsigned U6 = cvt_pk_bf16(p_[12], p_[13]), U7 = cvt_pk_bf16(p_[14], p_[15]); \
      PSWAP(U0, U2); PSWAP(U1, U3); PSWAP(U4, U6); PSWAP(U5, U7);              \
      BFrag F0, F1;                                                            \
      F0.u32[0] = U0; F0.u32[1] = U1; F0.u32[2] = U2; F0.u32[3] = U3;          \
      F1.u32[0] = U4; F1.u32[1] = U5; F1.u32[2] = U6; F1.u32[3] = U7;          \
      __builtin_amdgcn_s_setprio(1);                                           \
      _Pragma("unroll") for (int db = 0; db < 2; ++db) {                       \
        FragU vf0_, vf1_;                                                      \
        vf0_.u = *reinterpret_cast<const ushort8v*>(                           \
            Vsp + (BUF) * 8192 + ((db * 32 + q5) * 128 + (((2 * b) * 32 + hi * 16) ^ fsw))); \
        vf1_.u = *reinterpret_cast<const ushort8v*>(                           \
            Vsp + (BUF) * 8192 + ((db * 32 + q5) * 128 + (((2 * b + 1) * 32 + hi * 16) ^ fsw))); \
        if (db == 0) {                                                         \
          acc0 = __builtin_amdgcn_mfma_f32_32x32x16_bf16(vf0_.b, F0.b, acc0, 0, 0, 0); \
          acc0 = __builtin_amdgcn_mfma_f32_32x32x16_bf16(vf1_.b, F1.b, acc0, 0, 0, 0); \
        } else {                                                               \
          acc1 = __builtin_amdgcn_mfma_f32_32x32x16_bf16(vf0_.b, F0.b, acc1, 0, 0, 0); \
          acc1 = __builtin_amdgcn_mfma_f32_32x32x16_bf16(vf1_.b, F1.b, acc1, 0, 0, 0); \
        }                                                                      \
      }                                                                        \
      __builtin_amdgcn_s_setprio(0);                                           \
    }                                                                          \
  } while (0)

  ATTN_STAGE(0, 0);
  for (int it = 0; it < 16; it += 2) {
    ATTN_TILE(0, it);
    ATTN_TILE(1, it + 1);
  }

  // ---- combine splits + normalize + store ----
  // rsum covers this lane's hi-half kv; fold across hi within the split:
  const float rs = rsum + __shfl_xor(rsum, 32);

  __syncthreads();
  if (sp == 1) {
#pragma unroll
    for (int i = 0; i < 4; ++i) {
      f32x4 v0 = (f32x4){acc0[4*i], acc0[4*i+1], acc0[4*i+2], acc0[4*i+3]};
      f32x4 v1 = (f32x4){acc1[4*i], acc1[4*i+1], acc1[4*i+2], acc1[4*i+3]};
      *reinterpret_cast<f32x4*>(SMEM + wq * 8192 + l * 128 + i * 16)      = v0;
      *reinterpret_cast<f32x4*>(SMEM + wq * 8192 + l * 128 + 64 + i * 16) = v1;
    }
    *reinterpret_cast<float*>(SMEM + 32768 + wq * 256 + l * 4) = rs;
  }
  __syncthreads();
  if (sp == 0) {
    const float ors = *reinterpret_cast<const float*>(SMEM + 32768 + wq * 256 + l * 4);
    const float rin = 1.0f / (rs + ors);
    unsigned short* orow = Og + ((size_t)(n * S_LEN + qg)) * EMB + h * DHEAD + hi4;
#pragma unroll
    for (int db = 0; db < 2; ++db) {
#pragma unroll
      for (int t = 0; t < 4; ++t) {
        f32x4 pa = *reinterpret_cast<const f32x4*>(
            SMEM + wq * 8192 + l * 128 + db * 64 + t * 16);
        float a0, a1, a2, a3;
        if (db == 0) {
          a0 = (acc0[4*t]   + pa[0]) * rin; a1 = (acc0[4*t+1] + pa[1]) * rin;
          a2 = (acc0[4*t+2] + pa[2]) * rin; a3 = (acc0[4*t+3] + pa[3]) * rin;
        } else {
          a0 = (acc1[4*t]   + pa[0]) * rin; a1 = (acc1[4*t+1] + pa[1]) * rin;
          a2 = (acc1[4*t+2] + pa[2]) * rin; a3 = (acc1[4*t+3] + pa[3]) * rin;
        }
        uint2 pk;
        pk.x = cvt_pk_bf16(a0, a1);
        pk.y = cvt_pk_bf16(a2, a3);
        *reinterpret_cast<uint2*>(orow + db * 32 + t * 8) = pk;
      }
    }
  }
}

// ---------------------------------------------------------------- projection
__global__ __launch_bounds__(256) void out_proj(
    const unsigned short* __restrict__ A,   // bf16 [4096][1024]
    const unsigned short* __restrict__ W,   // bf16 [1024][1024]
    const float* __restrict__ bias,
    float* __restrict__ Y)                  // f32 [4096][1024]
{
  __shared__ __attribute__((aligned(16))) unsigned short At[2][8192];
  __shared__ __attribute__((aligned(16))) unsigned short Bt[2][4096];

  const int bid = blockIdx.x;
  const int nb = bid & 15, mb = bid >> 4;
  const int tid = threadIdx.x;
  const int w = tid >> 6, l = tid & 63, lg = l >> 4, li = l & 15;
  const int m0 = mb * 128, n0 = nb * 64;

  f32x4 acc[2][4];
#pragma unroll
  for (int g = 0; g < 2; ++g)
#pragma unroll
    for (int c = 0; c < 4; ++c) acc[g][c] = (f32x4){0.f, 0.f, 0.f, 0.f};

  const int srow8  = tid >> 3;
  const int schunk = (tid & 7) * 16;
  const int ssw    = (srow8 & 7) << 4;
  const char* abase = (const char*)A + ((size_t)m0 + srow8) * (EMB * 2) + (schunk ^ ssw);
  const char* bbase = (const char*)W + ((size_t)n0 + srow8) * (EMB * 2) + (schunk ^ ssw);
  const int rsw = (li & 7) << 4;

#define PROJ_STAGE(BUF, KK) do {                                               \
    const char* ab_ = abase + (KK) * 128;                                      \
    const char* bb_ = bbase + (KK) * 128;                                      \
    GLD16(ab_,             (char*)At + (BUF) * 16384 + w * 1024);              \
    GLD16(ab_ + 32 * 2048, (char*)At + (BUF) * 16384 + 4096 + w * 1024);       \
    GLD16(ab_ + 64 * 2048, (char*)At + (BUF) * 16384 + 8192 + w * 1024);       \
    GLD16(ab_ + 96 * 2048, (char*)At + (BUF) * 16384 + 12288 + w * 1024);      \
    GLD16(bb_,             (char*)Bt + (BUF) * 8192 + w * 1024);               \
    GLD16(bb_ + 32 * 2048, (char*)Bt + (BUF) * 8192 + 4096 + w * 1024);        \
  } while (0)

#define PROJ_TILE(BUF, KK) do {                                                \
    __syncthreads();                                                           \
    if ((KK) + 1 < 16) PROJ_STAGE((BUF) ^ 1, (KK) + 1);                        \
    __builtin_amdgcn_s_setprio(1);                                             \
    _Pragma("unroll") for (int s = 0; s < 2; ++s) {                            \
      FragU af_[2];                                                            \
      _Pragma("unroll") for (int g = 0; g < 2; ++g)                            \
        af_[g].u = *reinterpret_cast<const ushort8v*>(                         \
            (char*)At + (BUF) * 16384 +                                        \
            ((w * 32 + g * 16 + li) * 128 + ((s * 64 + lg * 16) ^ rsw)));      \
      _Pragma("unroll") for (int c = 0; c < 4; ++c) {                          \
        FragU bf_;                                                             \
        bf_.u = *reinterpret_cast<const ushort8v*>(                            \
            (char*)Bt + (BUF) * 8192 +                                         \
            ((c * 16 + li) * 128 + ((s * 64 + lg * 16) ^ rsw)));               \
        acc[0][c] = __builtin_amdgcn_mfma_f32_16x16x32_bf16(af_[0].b, bf_.b, acc[0][c], 0, 0, 0); \
        acc[1][c] = __builtin_amdgcn_mfma_f32_16x16x32_bf16(af_[1].b, bf_.b, acc[1][c], 0, 0, 0); \
      }                                                                        \
    }                                                                          \
    __builtin_amdgcn_s_setprio(0);                                             \
  } while (0)

  PROJ_STAGE(0, 0);
  for (int kk = 0; kk < 16; kk += 2) {
    PROJ_TILE(0, kk);
    PROJ_TILE(1, kk + 1);
  }

#pragma unroll
  for (int g = 0; g < 2; ++g)
#pragma unroll
    for (int c = 0; c < 4; ++c) {
      const float bv = bias[n0 + c * 16 + li];
#pragma unroll
      for (int r = 0; r < 4; ++r) {
        const int row = m0 + w * 32 + g * 16 + lg * 4 + r;
        Y[(size_t)row * EMB + n0 + c * 16 + li] = acc[g][c][r] + bv;
      }
    }
}

// ---------------------------------------------------------------- launch
extern "C" void kernel_launch(void* const* d_in, const int* in_sizes, int n_in,
                              void* d_out, int out_size, void* d_ws, size_t ws_size,
                              hipStream_t stream) {
  const float* Vg = (const float*)d_in[0];
  const float* Kg = (const float*)d_in[1];
  const float* Qg = (const float*)d_in[2];
  const int*   Mg = (const int*)d_in[3];
  const float* Wo = (const float*)d_in[4];
  const float* bo = (const float*)d_in[5];
  float* Y = (float*)d_out;

  char* ws = (char*)d_ws;
  unsigned short* Og   = (unsigned short*)(ws);                       //  8 MB
  unsigned short* Wb   = (unsigned short*)(ws + (8u << 20));          //  2 MB
  unsigned short* Kb16 = (unsigned short*)(ws + (10u << 20));         //  8 MB
  unsigned short* Vt   = (unsigned short*)(ws + (18u << 20));         //  8 MB
  u64*            Mbit = (u64*)(ws + (26u << 20));                    //  1 MB

  hipLaunchKernelGGL(prep, dim3(11776), dim3(256), 0, stream,
                     Wo, Wb, Kg, Kb16, Vg, Vt, Mg, Mbit);
  hipLaunchKernelGGL(attn_fwd, dim3(NBATCH * NHEAD * (S_LEN / 128)), dim3(512), 0, stream,
                     Kb16, Vt, Qg, Mbit, Og);
  hipLaunchKernelGGL(out_proj, dim3((NBATCH * S_LEN / 128) * (EMB / 64)), dim3(256), 0, stream,
                     Og, Wb, bo, Y);
}

// Round 10
// 88.918 us; speedup vs baseline: 1.3223x; 1.0800x over previous
//
#include <hip/hip_runtime.h>
#include <hip/hip_bf16.h>

// SelfAttention: N=2, S=2048, E=1024, H=16, D=64.
// Round 10: round-9 structure, softmax VALU diet: pre-scaled Q (no fma, no
// exp offset -- normalization-invariant), rowsum via ones-MFMA (no VALU adds,
// no epilogue shfl), sign-extend+AND masking, mask prefetch, swizzled
// epilogue exchange. prep/out_proj unchanged.

#define S_LEN  2048
#define EMB    1024
#define NHEAD  16
#define DHEAD  64
#define NBATCH 2

// log2(e)/32: folded into Q so QK^T lands pre-scaled for exp2
#define KSC 0.04508422002778011f

typedef float              f32x4    __attribute__((ext_vector_type(4)));
typedef float              f32x16   __attribute__((ext_vector_type(16)));
typedef __bf16             bf16x8   __attribute__((ext_vector_type(8)));
typedef unsigned short     ushort8v __attribute__((ext_vector_type(8)));
typedef unsigned long long u64;

union FragU { ushort8v u; bf16x8 b; };
union BFrag { unsigned u32[4]; bf16x8 b; };

__device__ __forceinline__ unsigned short f2b(float f) {
  union { __hip_bfloat16 h; unsigned short u; } c;
  c.h = __float2bfloat16(f);
  return c.u;
}

__device__ __forceinline__ unsigned int cvt_pk_bf16(float lo, float hi) {
  unsigned int r;
  asm("v_cvt_pk_bf16_f32 %0, %1, %2" : "=v"(r) : "v"(lo), "v"(hi));
  return r;
}

#define PSWAP(a, b) asm("v_permlane32_swap_b32 %0, %1" : "+v"(a), "+v"(b))

#define GLD16(g, l)                                                            \
  __builtin_amdgcn_global_load_lds(                                            \
      (__attribute__((address_space(1))) void*)(g),                            \
      (__attribute__((address_space(3))) void*)(l), 16, 0, 0)

// ------------------------------------------------------- fused prep kernel
__global__ __launch_bounds__(256) void prep(
    const float* __restrict__ Wo, unsigned short* __restrict__ Wb,
    const float* __restrict__ Kg, unsigned short* __restrict__ Kb,
    const float* __restrict__ Vg, unsigned short* __restrict__ Vt,
    const int* __restrict__ Mg,   u64* __restrict__ Mb)
{
  const int bid = blockIdx.x;
  const int tid = threadIdx.x;
  if (bid < 2560) {
    const float* X = (bid < 512) ? Wo : Kg;
    unsigned short* Y = (bid < 512) ? Wb : Kb;
    const int bb = (bid < 512) ? bid : bid - 512;
    const size_t i = ((size_t)bb * 256 + tid) * 8;
    float4 a = *reinterpret_cast<const float4*>(X + i);
    float4 b = *reinterpret_cast<const float4*>(X + i + 4);
    ushort8v u;
    u[0] = f2b(a.x); u[1] = f2b(a.y); u[2] = f2b(a.z); u[3] = f2b(a.w);
    u[4] = f2b(b.x); u[5] = f2b(b.y); u[6] = f2b(b.z); u[7] = f2b(b.w);
    *reinterpret_cast<ushort8v*>(Y + i) = u;
  } else if (bid < 3584) {
    __shared__ unsigned short T[64][72];
    const int b2 = bid - 2560;
    const int sb = b2 & 31, h = (b2 >> 5) & 15, n = b2 >> 9;
    const int r = tid >> 2, cb = (tid & 3) * 16;
    const float* src = Vg + ((size_t)(n * S_LEN + sb * 64 + r)) * EMB + h * DHEAD + cb;
    ushort8v u0, u1;
#pragma unroll
    for (int j = 0; j < 2; ++j) {
      float4 x = *reinterpret_cast<const float4*>(src + j * 4);
      u0[j*4+0] = f2b(x.x); u0[j*4+1] = f2b(x.y); u0[j*4+2] = f2b(x.z); u0[j*4+3] = f2b(x.w);
      float4 y = *reinterpret_cast<const float4*>(src + 8 + j * 4);
      u1[j*4+0] = f2b(y.x); u1[j*4+1] = f2b(y.y); u1[j*4+2] = f2b(y.z); u1[j*4+3] = f2b(y.w);
    }
    *reinterpret_cast<ushort8v*>(&T[r][cb])     = u0;
    *reinterpret_cast<ushort8v*>(&T[r][cb + 8]) = u1;
    __syncthreads();
    const int d = tid >> 2, sc_ = (tid & 3) * 16;
    ushort8v o0, o1;
#pragma unroll
    for (int j = 0; j < 8; ++j) { o0[j] = T[sc_ + j][d]; o1[j] = T[sc_ + 8 + j][d]; }
    unsigned short* dst = Vt + ((size_t)((n * NHEAD + h) * DHEAD + d)) * S_LEN + sb * 64 + sc_;
    *reinterpret_cast<ushort8v*>(dst)     = o0;
    *reinterpret_cast<ushort8v*>(dst + 8) = o1;
  } else {
    const int b3 = bid - 3584;
    const size_t base = (size_t)b3 * 1024 + (tid >> 6) * 256;
    const int l = tid & 63;
#pragma unroll
    for (int j = 0; j < 4; ++j) {
      const int v = Mg[base + j * 64 + l];
      u64 bj = __ballot(v != 0);
      if (l == 0) Mb[base / 64 + j] = bj;
    }
  }
}

// ---------------------------------------------------------------- attention
__global__ __launch_bounds__(512, 4) void attn_fwd(
    const unsigned short* __restrict__ Kb,   // bf16 [n][s][E]
    const unsigned short* __restrict__ Vtg,  // bf16 [n][h][d][s]
    const float* __restrict__ Qg,            // f32  [n][s][E]
    const u64* __restrict__ Mbit,            // [n][s][32]
    unsigned short* __restrict__ Og)         // bf16 [n][s][E]
{
  __shared__ __attribute__((aligned(16))) char SMEM[65536];

  const int bid = blockIdx.x;
  const int qb = bid & 15, h = (bid >> 4) & 15, n = bid >> 8;
  const int nh = n * NHEAD + h;
  const int tid = threadIdx.x;
  const int w = tid >> 6, sp = w >> 2, wq = w & 3;
  const int l = tid & 63, q5 = l & 31, hi = l >> 5;
  const int hi4 = hi * 4;
  const int q0w = qb * 128 + wq * 32;
  const int qg = q0w + q5;

  // Q fragments pre-scaled by log2e/32 (exp2 input comes straight from MFMA)
  FragU qf[4];
  {
    const float* qp = Qg + ((size_t)(n * S_LEN + qg)) * EMB + h * DHEAD + hi * 8;
#pragma unroll
    for (int s = 0; s < 4; ++s) {
      float4 a = *reinterpret_cast<const float4*>(qp + s * 16);
      float4 b = *reinterpret_cast<const float4*>(qp + s * 16 + 4);
      ushort8v u;
      u[0] = f2b(a.x * KSC); u[1] = f2b(a.y * KSC); u[2] = f2b(a.z * KSC); u[3] = f2b(a.w * KSC);
      u[4] = f2b(b.x * KSC); u[5] = f2b(b.y * KSC); u[6] = f2b(b.z * KSC); u[7] = f2b(b.w * KSC);
      qf[s].u = u;
    }
  }

  FragU ones;
#pragma unroll
  for (int j = 0; j < 8; ++j) ones.u[j] = 0x3F80;

  f32x16 acc0 = {}, acc1 = {}, racc = {};

  const int t8 = tid & 255;
  const int srow = t8 >> 3, sc = t8 & 7;
  const char* kbase = (const char*)Kb +
      ((size_t)(n * S_LEN + sp * 1024 + srow)) * 2048 + h * 128 +
      ((sc * 16) ^ ((srow & 7) << 4));
  const char* vbase = (const char*)Vtg +
      ((size_t)(nh * DHEAD + srow)) * 4096 + sp * 2048 +
      ((sc * 16) ^ ((srow & 7) << 4));

  char* Ksp = SMEM + sp * 16384;
  char* Vsp = SMEM + 32768 + sp * 16384;
  const int fsw = (l & 7) << 4;

  const u64* Mq = Mbit + ((size_t)(n * S_LEN + qg)) * 32 + sp * 16;
  u64 mq_cur = Mq[0];

#define ATTN_STAGE(BUF, IT) do {                                               \
    GLD16(kbase + (size_t)(IT) * 131072,          Ksp + (BUF) * 8192 + t8 * 16); \
    GLD16(kbase + (size_t)(IT) * 131072 + 65536,  Ksp + (BUF) * 8192 + 4096 + t8 * 16); \
    GLD16(vbase + (size_t)(IT) * 128,             Vsp + (BUF) * 8192 + t8 * 16); \
    GLD16(vbase + (size_t)(IT) * 128 + 131072,    Vsp + (BUF) * 8192 + 4096 + t8 * 16); \
  } while (0)

#define ATTN_TILE(BUF, IT) do {                                                \
    __syncthreads();                                                           \
    if ((IT) + 1 < 16) ATTN_STAGE((BUF) ^ 1, (IT) + 1);                        \
    const u64 mrow_ = mq_cur;                                                  \
    if ((IT) + 1 < 16) mq_cur = Mq[(IT) + 1];                                  \
    _Pragma("unroll") for (int b = 0; b < 2; ++b) {                            \
      f32x16 Sb = {};                                                          \
      __builtin_amdgcn_s_setprio(1);                                           \
      _Pragma("unroll") for (int s = 0; s < 4; ++s) {                          \
        FragU kf_;                                                             \
        kf_.u = *reinterpret_cast<const ushort8v*>(                            \
            Ksp + (BUF) * 8192 + ((b * 32 + q5) * 128 + ((s * 32 + hi * 16) ^ fsw))); \
        Sb = __builtin_amdgcn_mfma_f32_32x32x16_bf16(kf_.b, qf[s].b, Sb, 0, 0, 0); \
      }                                                                        \
      __builtin_amdgcn_s_setprio(0);                                           \
      const unsigned m32_ = b ? (unsigned)(mrow_ >> 32) : (unsigned)mrow_;     \
      float p_[16];                                                            \
      _Pragma("unroll") for (int t = 0; t < 4; ++t) {                          \
        const unsigned nib_ = m32_ >> (8 * t + hi4);                           \
        _Pragma("unroll") for (int e = 0; e < 4; ++e) {                        \
          const int r = 4 * t + e;                                             \
          float ex_ = __builtin_amdgcn_exp2f(Sb[r]);                           \
          const unsigned sm_ = (unsigned)((int)(nib_ << (31 - e)) >> 31);      \
          p_[r] = __uint_as_float(__float_as_uint(ex_) & sm_);                 \
        }                                                                      \
      }                                                                        \
      unsigned U0 = cvt_pk_bf16(p_[0],  p_[1]),  U1 = cvt_pk_bf16(p_[2],  p_[3]); \
      unsigned U2 = cvt_pk_bf16(p_[4],  p_[5]),  U3 = cvt_pk_bf16(p_[6],  p_[7]); \
      unsigned U4 = cvt_pk_bf16(p_[8],  p_[9]),  U5 = cvt_pk_bf16(p_[10], p_[11]); \
      unsigned U6 = cvt_pk_bf16(p_[12], p_[13]), U7 = cvt_pk_bf16(p_[14], p_[15]); \
      PSWAP(U0, U2); PSWAP(U1, U3); PSWAP(U4, U6); PSWAP(U5, U7);              \
      BFrag F0, F1;                                                            \
      F0.u32[0] = U0; F0.u32[1] = U1; F0.u32[2] = U2; F0.u32[3] = U3;          \
      F1.u32[0] = U4; F1.u32[1] = U5; F1.u32[2] = U6; F1.u32[3] = U7;          \
      __builtin_amdgcn_s_setprio(1);                                           \
      racc = __builtin_amdgcn_mfma_f32_32x32x16_bf16(ones.b, F0.b, racc, 0, 0, 0); \
      racc = __builtin_amdgcn_mfma_f32_32x32x16_bf16(ones.b, F1.b, racc, 0, 0, 0); \
      _Pragma("unroll") for (int db = 0; db < 2; ++db) {                       \
        FragU vf0_, vf1_;                                                      \
        vf0_.u = *reinterpret_cast<const ushort8v*>(                           \
            Vsp + (BUF) * 8192 + ((db * 32 + q5) * 128 + (((2 * b) * 32 + hi * 16) ^ fsw))); \
        vf1_.u = *reinterpret_cast<const ushort8v*>(                           \
            Vsp + (BUF) * 8192 + ((db * 32 + q5) * 128 + (((2 * b + 1) * 32 + hi * 16) ^ fsw))); \
        if (db == 0) {                                                         \
          acc0 = __builtin_amdgcn_mfma_f32_32x32x16_bf16(vf0_.b, F0.b, acc0, 0, 0, 0); \
          acc0 = __builtin_amdgcn_mfma_f32_32x32x16_bf16(vf1_.b, F1.b, acc0, 0, 0, 0); \
        } else {                                                               \
          acc1 = __builtin_amdgcn_mfma_f32_32x32x16_bf16(vf0_.b, F0.b, acc1, 0, 0, 0); \
          acc1 = __builtin_amdgcn_mfma_f32_32x32x16_bf16(vf1_.b, F1.b, acc1, 0, 0, 0); \
        }                                                                      \
      }                                                                        \
      __builtin_amdgcn_s_setprio(0);                                           \
    }                                                                          \
  } while (0)

  ATTN_STAGE(0, 0);
  for (int it = 0; it < 16; it += 2) {
    ATTN_TILE(0, it);
    ATTN_TILE(1, it + 1);
  }

  // ---- combine splits + normalize + store ----
  const float rs = racc[0];   // ones-MFMA: every row holds the full kv-sum
  const int esw = (l & 7) << 4;

  __syncthreads();
  if (sp == 1) {
#pragma unroll
    for (int i = 0; i < 4; ++i) {
      f32x4 v0 = (f32x4){acc0[4*i], acc0[4*i+1], acc0[4*i+2], acc0[4*i+3]};
      f32x4 v1 = (f32x4){acc1[4*i], acc1[4*i+1], acc1[4*i+2], acc1[4*i+3]};
      *reinterpret_cast<f32x4*>(SMEM + wq * 8192 + l * 128 + ((i * 16) ^ esw))      = v0;
      *reinterpret_cast<f32x4*>(SMEM + wq * 8192 + l * 128 + ((64 + i * 16) ^ esw)) = v1;
    }
    *reinterpret_cast<float*>(SMEM + 32768 + wq * 256 + l * 4) = rs;
  }
  __syncthreads();
  if (sp == 0) {
    const float ors = *reinterpret_cast<const float*>(SMEM + 32768 + wq * 256 + l * 4);
    const float rin = 1.0f / (rs + ors);
    unsigned short* orow = Og + ((size_t)(n * S_LEN + qg)) * EMB + h * DHEAD + hi4;
#pragma unroll
    for (int db = 0; db < 2; ++db) {
#pragma unroll
      for (int t = 0; t < 4; ++t) {
        f32x4 pa = *reinterpret_cast<const f32x4*>(
            SMEM + wq * 8192 + l * 128 + ((db * 64 + t * 16) ^ esw));
        float a0, a1, a2, a3;
        if (db == 0) {
          a0 = (acc0[4*t]   + pa[0]) * rin; a1 = (acc0[4*t+1] + pa[1]) * rin;
          a2 = (acc0[4*t+2] + pa[2]) * rin; a3 = (acc0[4*t+3] + pa[3]) * rin;
        } else {
          a0 = (acc1[4*t]   + pa[0]) * rin; a1 = (acc1[4*t+1] + pa[1]) * rin;
          a2 = (acc1[4*t+2] + pa[2]) * rin; a3 = (acc1[4*t+3] + pa[3]) * rin;
        }
        uint2 pk;
        pk.x = cvt_pk_bf16(a0, a1);
        pk.y = cvt_pk_bf16(a2, a3);
        *reinterpret_cast<uint2*>(orow + db * 32 + t * 8) = pk;
      }
    }
  }
}

// ---------------------------------------------------------------- projection
__global__ __launch_bounds__(256) void out_proj(
    const unsigned short* __restrict__ A,   // bf16 [4096][1024]
    const unsigned short* __restrict__ W,   // bf16 [1024][1024]
    const float* __restrict__ bias,
    float* __restrict__ Y)                  // f32 [4096][1024]
{
  __shared__ __attribute__((aligned(16))) unsigned short At[2][8192];
  __shared__ __attribute__((aligned(16))) unsigned short Bt[2][4096];

  const int bid = blockIdx.x;
  const int nb = bid & 15, mb = bid >> 4;
  const int tid = threadIdx.x;
  const int w = tid >> 6, l = tid & 63, lg = l >> 4, li = l & 15;
  const int m0 = mb * 128, n0 = nb * 64;

  f32x4 acc[2][4];
#pragma unroll
  for (int g = 0; g < 2; ++g)
#pragma unroll
    for (int c = 0; c < 4; ++c) acc[g][c] = (f32x4){0.f, 0.f, 0.f, 0.f};

  const int srow8  = tid >> 3;
  const int schunk = (tid & 7) * 16;
  const int ssw    = (srow8 & 7) << 4;
  const char* abase = (const char*)A + ((size_t)m0 + srow8) * (EMB * 2) + (schunk ^ ssw);
  const char* bbase = (const char*)W + ((size_t)n0 + srow8) * (EMB * 2) + (schunk ^ ssw);
  const int rsw = (li & 7) << 4;

#define PROJ_STAGE(BUF, KK) do {                                               \
    const char* ab_ = abase + (KK) * 128;                                      \
    const char* bb_ = bbase + (KK) * 128;                                      \
    GLD16(ab_,             (char*)At + (BUF) * 16384 + w * 1024);              \
    GLD16(ab_ + 32 * 2048, (char*)At + (BUF) * 16384 + 4096 + w * 1024);       \
    GLD16(ab_ + 64 * 2048, (char*)At + (BUF) * 16384 + 8192 + w * 1024);       \
    GLD16(ab_ + 96 * 2048, (char*)At + (BUF) * 16384 + 12288 + w * 1024);      \
    GLD16(bb_,             (char*)Bt + (BUF) * 8192 + w * 1024);               \
    GLD16(bb_ + 32 * 2048, (char*)Bt + (BUF) * 8192 + 4096 + w * 1024);        \
  } while (0)

#define PROJ_TILE(BUF, KK) do {                                                \
    __syncthreads();                                                           \
    if ((KK) + 1 < 16) PROJ_STAGE((BUF) ^ 1, (KK) + 1);                        \
    __builtin_amdgcn_s_setprio(1);                                             \
    _Pragma("unroll") for (int s = 0; s < 2; ++s) {                            \
      FragU af_[2];                                                            \
      _Pragma("unroll") for (int g = 0; g < 2; ++g)                            \
        af_[g].u = *reinterpret_cast<const ushort8v*>(                         \
            (char*)At + (BUF) * 16384 +                                        \
            ((w * 32 + g * 16 + li) * 128 + ((s * 64 + lg * 16) ^ rsw)));      \
      _Pragma("unroll") for (int c = 0; c < 4; ++c) {                          \
        FragU bf_;                                                             \
        bf_.u = *reinterpret_cast<const ushort8v*>(                            \
            (char*)Bt + (BUF) * 8192 +                                         \
            ((c * 16 + li) * 128 + ((s * 64 + lg * 16) ^ rsw)));               \
        acc[0][c] = __builtin_amdgcn_mfma_f32_16x16x32_bf16(af_[0].b, bf_.b, acc[0][c], 0, 0, 0); \
        acc[1][c] = __builtin_amdgcn_mfma_f32_16x16x32_bf16(af_[1].b, bf_.b, acc[1][c], 0, 0, 0); \
      }                                                                        \
    }                                                                          \
    __builtin_amdgcn_s_setprio(0);                                             \
  } while (0)

  PROJ_STAGE(0, 0);
  for (int kk = 0; kk < 16; kk += 2) {
    PROJ_TILE(0, kk);
    PROJ_TILE(1, kk + 1);
  }

#pragma unroll
  for (int g = 0; g < 2; ++g)
#pragma unroll
    for (int c = 0; c < 4; ++c) {
      const float bv = bias[n0 + c * 16 + li];
#pragma unroll
      for (int r = 0; r < 4; ++r) {
        const int row = m0 + w * 32 + g * 16 + lg * 4 + r;
        Y[(size_t)row * EMB + n0 + c * 16 + li] = acc[g][c][r] + bv;
      }
    }
}

// ---------------------------------------------------------------- launch
extern "C" void kernel_launch(void* const* d_in, const int* in_sizes, int n_in,
                              void* d_out, int out_size, void* d_ws, size_t ws_size,
                              hipStream_t stream) {
  const float* Vg = (const float*)d_in[0];
  const float* Kg = (const float*)d_in[1];
  const float* Qg = (const float*)d_in[2];
  const int*   Mg = (const int*)d_in[3];
  const float* Wo = (const float*)d_in[4];
  const float* bo = (const float*)d_in[5];
  float* Y = (float*)d_out;

  char* ws = (char*)d_ws;
  unsigned short* Og   = (unsigned short*)(ws);                       //  8 MB
  unsigned short* Wb   = (unsigned short*)(ws + (8u << 20));          //  2 MB
  unsigned short* Kb16 = (unsigned short*)(ws + (10u << 20));         //  8 MB
  unsigned short* Vt   = (unsigned short*)(ws + (18u << 20));         //  8 MB
  u64*            Mbit = (u64*)(ws + (26u << 20));                    //  1 MB

  hipLaunchKernelGGL(prep, dim3(11776), dim3(256), 0, stream,
                     Wo, Wb, Kg, Kb16, Vg, Vt, Mg, Mbit);
  hipLaunchKernelGGL(attn_fwd, dim3(NBATCH * NHEAD * (S_LEN / 128)), dim3(512), 0, stream,
                     Kb16, Vt, Qg, Mbit, Og);
  hipLaunchKernelGGL(out_proj, dim3((NBATCH * S_LEN / 128) * (EMB / 64)), dim3(256), 0, stream,
                     Og, Wb, bo, Y);
}